// Round 2
// baseline (876.850 us; speedup 1.0000x reference)
//
#include <hip/hip_runtime.h>
#include <math.h>

#define LRES 8192
#define TOPK 30

// EDGES[:,0] (atom at residue i) and EDGES[:,1] (atom at neighbor j)
__device__ __constant__ int c_ea[25] = {1,0,2,3,4,1,1,1,1,0,0,0,4,4,3,0,2,3,4,2,3,4,2,3,2};
__device__ __constant__ int c_eb[25] = {1,0,2,3,4,0,2,3,4,2,3,4,2,3,2,1,1,1,1,0,0,0,4,4,3};

// ---------------------------------------------------------------- prep: Y5 + packed Ca
__global__ __launch_bounds__(256) void prep_kernel(const float* __restrict__ X,
                                                   float* __restrict__ Y5,
                                                   float* __restrict__ CaP) {
    int i = blockIdx.x * 256 + threadIdx.x;
    const float* x = X + i * 12;
    float N0 = x[0], N1 = x[1], N2 = x[2];
    float A0 = x[3], A1 = x[4], A2 = x[5];   // Ca
    float C0 = x[6], C1 = x[7], C2 = x[8];
    float O0 = x[9], O1 = x[10], O2 = x[11];
    float bx = A0 - N0, by = A1 - N1, bz = A2 - N2;
    float cx = C0 - A0, cy = C1 - A1, cz = C2 - A2;
    float rx = by * cz - bz * cy;
    float ry = bz * cx - bx * cz;
    float rz = bx * cy - by * cx;
    float Bx = -0.58273431f * rx + 0.56802827f * bx - 0.54067466f * cx + A0;
    float By = -0.58273431f * ry + 0.56802827f * by - 0.54067466f * cy + A1;
    float Bz = -0.58273431f * rz + 0.56802827f * bz - 0.54067466f * cz + A2;
    float* y = Y5 + i * 15;
    y[0] = N0; y[1] = N1; y[2] = N2;
    y[3] = A0; y[4] = A1; y[5] = A2;
    y[6] = C0; y[7] = C1; y[8] = C2;
    y[9] = O0; y[10] = O1; y[11] = O2;
    y[12] = Bx; y[13] = By; y[14] = Bz;
    CaP[i * 3 + 0] = A0; CaP[i * 3 + 1] = A1; CaP[i * 3 + 2] = A2;
}

// ------------------------------------------- positional table T[66][128] = (pe_w[d]+pe_b) @ W[0:16]
__global__ __launch_bounds__(256) void pet_kernel(const float* __restrict__ pe_w,
                                                  const float* __restrict__ pe_b,
                                                  const float* __restrict__ edge_w,
                                                  float* __restrict__ T) {
    int idx = blockIdx.x * 256 + threadIdx.x;
    if (idx >= 66 * 128) return;
    int d = idx >> 7, c = idx & 127;
    float acc = 0.f;
    #pragma unroll
    for (int r = 0; r < 16; ++r)
        acc += (pe_w[d * 16 + r] + pe_b[r]) * edge_w[r * 128 + c];
    T[idx] = acc;
}

// ---------------------------------------------------------------- exact top-30 per row (f64 order)
__global__ __launch_bounds__(256) void topk_kernel(const float* __restrict__ CaP,
                                                   const float* __restrict__ mask,
                                                   int* __restrict__ eidx,
                                                   float* __restrict__ eidx_f) {
    int row = blockIdx.x;
    int tid = threadIdx.x;
    __shared__ unsigned long long sKey[256];
    __shared__ int sIdx[256];
    __shared__ int sWin;

    double cax = (double)CaP[row * 3 + 0];
    double cay = (double)CaP[row * 3 + 1];
    double caz = (double)CaP[row * 3 + 2];
    float mi = mask[row];

    unsigned long long key[32];
    #pragma unroll
    for (int t = 0; t < 32; ++t) {
        int j = tid + (t << 8);
        double dx = (double)CaP[j * 3 + 0] - cax;
        double dy = (double)CaP[j * 3 + 1] - cay;
        double dz = (double)CaP[j * 3 + 2] - caz;
        double s = dx * dx + dy * dy + dz * dz;   // >=0: bit pattern is order-monotone
        unsigned long long kb = __double_as_longlong(s);
        if (mi * mask[j] == 0.0f) kb = 0xFFFFFFFFFFFFFFFFull;
        key[t] = kb;
    }
    // per-thread cached minimum
    unsigned long long bk = key[0]; int bj = tid;
    #pragma unroll
    for (int t = 1; t < 32; ++t) {
        if (key[t] < bk) { bk = key[t]; bj = tid + (t << 8); }
    }
    sKey[tid] = bk; sIdx[tid] = bj;

    for (int it = 0; it < TOPK; ++it) {
        __syncthreads();
        if (tid < 64) {
            unsigned long long k0 = sKey[tid]; int j0 = sIdx[tid];
            #pragma unroll
            for (int q = 1; q < 4; ++q) {
                unsigned long long kq = sKey[tid + 64 * q]; int jq = sIdx[tid + 64 * q];
                if (kq < k0 || (kq == k0 && jq < j0)) { k0 = kq; j0 = jq; }
            }
            #pragma unroll
            for (int off = 32; off >= 1; off >>= 1) {
                unsigned long long ko = __shfl_down(k0, off);
                int jo = __shfl_down(j0, off);
                if (ko < k0 || (ko == k0 && jo < j0)) { k0 = ko; j0 = jo; }
            }
            if (tid == 0) {
                sWin = j0;
                eidx[row * TOPK + it] = j0;
                eidx_f[row * TOPK + it] = (float)j0;
            }
        }
        __syncthreads();
        int jw = sWin;
        if ((jw & 255) == tid) {          // only the losing thread rescans
            int ts = jw >> 8;
            #pragma unroll
            for (int t = 0; t < 32; ++t)
                if (t == ts) key[t] = 0xFFFFFFFFFFFFFFFFull;
            unsigned long long nk = key[0]; int nj = tid;
            #pragma unroll
            for (int t = 1; t < 32; ++t) {
                if (key[t] < nk) { nk = key[t]; nj = tid + (t << 8); }
            }
            sKey[tid] = nk; sIdx[tid] = nj;
        }
    }
}

// ---------------------------------------------------------------- edge features + GEMM + LN
// One WG = 256 threads handles 64 edges x 128 outputs. K = 400 RBF feats in 5 chunks of 80.
__global__ __launch_bounds__(256) void edge_kernel(const float* __restrict__ Y5,
                                                   const float* __restrict__ Tt,
                                                   const int* __restrict__ eidx,
                                                   const int* __restrict__ residue_idx,
                                                   const int* __restrict__ chain_idx,
                                                   const float* __restrict__ edge_w,
                                                   const float* __restrict__ ln_scale,
                                                   const float* __restrict__ ln_offset,
                                                   float* __restrict__ out) {
    __shared__ __attribute__((aligned(16))) float sDist[25][64];
    __shared__ int sD[64];
    __shared__ __attribute__((aligned(16))) float sA[80][64];
    __shared__ __attribute__((aligned(16))) float sW[80][128];

    int tid = threadIdx.x;
    int m0 = blockIdx.x * 64;

    // ---- phase 1: per-edge metadata + 25 atom-pair distances (4 threads per edge)
    {
        int e = tid >> 2, q = tid & 3;
        int m = m0 + e;
        int i = m / 30;
        int j = eidx[m];
        if (q == 0) {
            int off = residue_idx[i] - residue_idx[j];
            int same = (chain_idx[i] == chain_idx[j]) ? 1 : 0;
            int dcl = off + 32;
            dcl = dcl < 0 ? 0 : (dcl > 64 ? 64 : dcl);
            sD[e] = same ? dcl : 65;
        }
        float yi[15], yj[15];
        const float* pi = Y5 + i * 15;
        const float* pj = Y5 + j * 15;
        #pragma unroll
        for (int t = 0; t < 15; ++t) { yi[t] = pi[t]; yj[t] = pj[t]; }
        #pragma unroll
        for (int e25 = 0; e25 < 25; ++e25) {
            if ((e25 & 3) == q) {
                int a = c_ea[e25], b = c_eb[e25];
                float dx = yi[a * 3 + 0] - yj[b * 3 + 0];
                float dy = yi[a * 3 + 1] - yj[b * 3 + 1];
                float dz = yi[a * 3 + 2] - yj[b * 3 + 2];
                sDist[e25][e] = sqrtf(dx * dx + dy * dy + dz * dz + 1e-6f);
            }
        }
    }

    float acc[8][4];
    #pragma unroll
    for (int r = 0; r < 8; ++r)
        #pragma unroll
        for (int c = 0; c < 4; ++c) acc[r][c] = 0.f;

    int cg = tid & 31, rg = tid >> 5;
    int c0 = cg * 4, r0 = rg * 8;

    for (int kc = 0; kc < 400; kc += 80) {
        __syncthreads();   // phase1->gen on first iter; compute->overwrite later
        // generate RBF tile sA[k][r] (k = feature within chunk, r = edge)
        #pragma unroll
        for (int p = 0; p < 20; ++p) {
            int idx = tid + 256 * p;
            int k = idx >> 6, r = idx & 63;
            int kf = kc + k;
            int e25 = kf >> 4, rr = kf & 15;
            float mu = 2.0f + (20.0f / 15.0f) * (float)rr;
            float xv = (sDist[e25][r] - mu) * 0.8f;   // /1.25
            sA[k][r] = __expf(-xv * xv);
        }
        // stage W2 chunk (rows 16+kc .. 16+kc+79, all 128 cols, contiguous)
        const float* wsrc = edge_w + (16 + kc) * 128;
        #pragma unroll
        for (int p = 0; p < 10; ++p) {
            int f = tid + 256 * p;
            *reinterpret_cast<float4*>(&sW[0][0] + f * 4) =
                *reinterpret_cast<const float4*>(wsrc + f * 4);
        }
        __syncthreads();
        for (int k = 0; k < 80; ++k) {
            float4 a0 = *reinterpret_cast<float4*>(&sA[k][r0]);
            float4 a1 = *reinterpret_cast<float4*>(&sA[k][r0 + 4]);
            float4 w  = *reinterpret_cast<float4*>(&sW[k][c0]);
            acc[0][0] += a0.x * w.x; acc[0][1] += a0.x * w.y; acc[0][2] += a0.x * w.z; acc[0][3] += a0.x * w.w;
            acc[1][0] += a0.y * w.x; acc[1][1] += a0.y * w.y; acc[1][2] += a0.y * w.z; acc[1][3] += a0.y * w.w;
            acc[2][0] += a0.z * w.x; acc[2][1] += a0.z * w.y; acc[2][2] += a0.z * w.z; acc[2][3] += a0.z * w.w;
            acc[3][0] += a0.w * w.x; acc[3][1] += a0.w * w.y; acc[3][2] += a0.w * w.z; acc[3][3] += a0.w * w.w;
            acc[4][0] += a1.x * w.x; acc[4][1] += a1.x * w.y; acc[4][2] += a1.x * w.z; acc[4][3] += a1.x * w.w;
            acc[5][0] += a1.y * w.x; acc[5][1] += a1.y * w.y; acc[5][2] += a1.y * w.z; acc[5][3] += a1.y * w.w;
            acc[6][0] += a1.z * w.x; acc[6][1] += a1.z * w.y; acc[6][2] += a1.z * w.z; acc[6][3] += a1.z * w.w;
            acc[7][0] += a1.w * w.x; acc[7][1] += a1.w * w.y; acc[7][2] += a1.w * w.z; acc[7][3] += a1.w * w.w;
        }
    }

    // ---- epilogue: + positional table, LayerNorm over 128, store
    float4 scl = *reinterpret_cast<const float4*>(ln_scale + c0);
    float4 ofs = *reinterpret_cast<const float4*>(ln_offset + c0);
    #pragma unroll
    for (int rr = 0; rr < 8; ++rr) {
        int m = m0 + r0 + rr;
        int d = sD[r0 + rr];
        float4 t4 = *reinterpret_cast<const float4*>(Tt + d * 128 + c0);
        float v0 = acc[rr][0] + t4.x;
        float v1 = acc[rr][1] + t4.y;
        float v2 = acc[rr][2] + t4.z;
        float v3 = acc[rr][3] + t4.w;
        float s = v0 + v1 + v2 + v3;
        #pragma unroll
        for (int off = 16; off >= 1; off >>= 1) s += __shfl_xor(s, off);
        float mu = s * (1.0f / 128.0f);
        float d0 = v0 - mu, d1 = v1 - mu, d2 = v2 - mu, d3 = v3 - mu;
        float sq = d0 * d0 + d1 * d1 + d2 * d2 + d3 * d3;
        #pragma unroll
        for (int off = 16; off >= 1; off >>= 1) sq += __shfl_xor(sq, off);
        float rs = rsqrtf(sq * (1.0f / 128.0f) + 1e-5f);
        float4 o;
        o.x = d0 * rs * scl.x + ofs.x;
        o.y = d1 * rs * scl.y + ofs.y;
        o.z = d2 * rs * scl.z + ofs.z;
        o.w = d3 * rs * scl.w + ofs.w;
        *reinterpret_cast<float4*>(out + (size_t)m * 128 + c0) = o;
    }
}

extern "C" void kernel_launch(void* const* d_in, const int* in_sizes, int n_in,
                              void* d_out, int out_size, void* d_ws, size_t ws_size,
                              hipStream_t stream) {
    const float* X           = (const float*)d_in[0];
    const float* mask        = (const float*)d_in[1];
    const int*   residue_idx = (const int*)d_in[2];
    const int*   chain_idx   = (const int*)d_in[3];
    const float* pe_w        = (const float*)d_in[4];
    const float* pe_b        = (const float*)d_in[5];
    const float* edge_w      = (const float*)d_in[6];
    const float* ln_scale    = (const float*)d_in[7];
    const float* ln_offset   = (const float*)d_in[8];

    float* out = (float*)d_out;

    // workspace layout (floats)
    float* base = (float*)d_ws;
    float* Y5   = base;                     // 8192*15 = 122880
    float* CaP  = base + 122880;            // 8192*3  = 24576
    float* Tt   = base + 147456;            // 66*128  = 8448
    int*   eidx = (int*)(base + 155904);    // 8192*30 ints

    float* E     = out;                     // 8192*30*128 floats
    float* eidxf = out + 31457280;          // 8192*30 floats (harness reads d_out as f32)

    prep_kernel<<<LRES / 256, 256, 0, stream>>>(X, Y5, CaP);
    pet_kernel<<<(66 * 128 + 255) / 256, 256, 0, stream>>>(pe_w, pe_b, edge_w, Tt);
    topk_kernel<<<LRES, 256, 0, stream>>>(CaP, mask, eidx, eidxf);
    edge_kernel<<<(LRES * TOPK) / 64, 256, 0, stream>>>(Y5, Tt, eidx, residue_idx,
                                                        chain_idx, edge_w, ln_scale,
                                                        ln_offset, E);
}